// Round 4
// baseline (98.477 us; speedup 1.0000x reference)
//
#include <hip/hip_runtime.h>

// Problem constants (from reference): N=32768, H=6, W=8, C=14
constexpr int kN        = 32768;
constexpr int kCells    = 32768 * 6 * 8;        // 1,572,864 cells
constexpr int kThreads  = 256;                  // 4 waves / block
constexpr int kGrid     = 2048;                 // blocks
constexpr int kChunksPerBlk = 3;                // 2048*256*3 = kCells (exact)
constexpr int kCellB    = 56;                   // 14 floats per cell
constexpr int kWaveB    = 64 * kCellB;          // 3584 B per tensor per wave
constexpr int kWaveTot  = 2 * kWaveB;           // 7168 B per wave (o + g)

constexpr float LAMBDA_COORD = 8.0f;
constexpr float LAMBDA_NOOBJ = 1.0f;
constexpr float LAMBDA_CLASS = 0.7f;
constexpr float EPS          = 1e-10f;

__device__ __forceinline__ float iou_box(float bx, float by, float bsw, float bsh,
                                         float gx, float gy, float gsw, float gsh) {
    float w1 = bsw * bsw, h1 = bsh * bsh;
    float w2 = gsw * gsw, h2 = gsh * gsh;
    float left  = fmaxf(bx - 0.5f * w1, gx - 0.5f * w2);
    float right = fminf(bx + 0.5f * w1, gx + 0.5f * w2);
    float top   = fmaxf(by - 0.5f * h1, gy - 0.5f * h2);
    float bot   = fminf(by + 0.5f * h1, gy + 0.5f * h2);
    float inter = fmaxf(right - left, 0.0f) * fmaxf(bot - top, 0.0f);
    float uni   = w1 * h1 + w2 * h2 - inter;
    return inter / (uni + EPS);
}

__device__ __forceinline__ float cell_loss(const float* o, const float* g) {
    float obj   = (g[4] > 0.0f) ? 1.0f : 0.0f;
    float noobj = 1.0f - obj;

    float iou0 = iou_box(o[0], o[1], o[2], o[3], g[0], g[1], g[2], g[3]);
    float iou1 = iou_box(o[5], o[6], o[7], o[8], g[0], g[1], g[2], g[3]);
    bool  s1   = iou1 > iou0;            // jnp.argmax picks first on ties -> idx=1 iff iou1>iou0
    float max_iou = fmaxf(iou0, iou1);

    float pr0 = s1 ? o[5] : o[0];
    float pr1 = s1 ? o[6] : o[1];
    float pr2 = s1 ? o[7] : o[2];
    float pr3 = s1 ? o[8] : o[3];
    float pr4 = s1 ? o[9] : o[4];
    float po4 = s1 ? o[4] : o[9];        // other pred conf

    float gr0 = s1 ? g[5] : g[0];
    float gr1 = s1 ? g[6] : g[1];
    float gr2 = s1 ? g[7] : g[2];
    float gr3 = s1 ? g[8] : g[3];
    float gn4 = s1 ? g[4] : g[9];        // other gt conf

    float d4 = o[4] - g[4], d9 = o[9] - g[9];
    float no_loss = noobj * (d4 * d4 + d9 * d9);

    float dcf  = pr4 - max_iou;
    float conf = dcf * dcf;

    float l0 = pr0 - gr0, l1 = pr1 - gr1, l2 = pr2 - gr2, l3 = pr3 - gr3;
    float loc = l0 * l0 + l1 * l1 + l2 * l2 + l3 * l3;

    float dnb = po4 - gn4;
    float nbc = dnb * dnb;

    float cls = 0.0f;
#pragma unroll
    for (int c = 10; c < 14; ++c) { float d = o[c] - g[c]; cls += d * d; }

    return LAMBDA_NOOBJ * no_loss +
           obj * (conf + LAMBDA_COORD * loc + LAMBDA_NOOBJ * nbc + LAMBDA_CLASS * cls);
}

// Async global->LDS, 16 B per lane. LDS dest = wave-uniform base + lane*16 (HW rule);
// GLOBAL source address is per-lane (may even point at different tensors per lane).
__device__ __forceinline__ void gl_lds16(const void* g, void* l) {
    __builtin_amdgcn_global_load_lds(
        (const __attribute__((address_space(1))) unsigned int*)g,
        (__attribute__((address_space(3))) unsigned int*)l,
        16 /*bytes, literal*/, 0 /*offset*/, 0 /*aux*/);
}

__global__ __launch_bounds__(256) void yolo_fused(const float* __restrict__ outp,
                                                  const float* __restrict__ gtp,
                                                  float* __restrict__ partial,
                                                  unsigned int* __restrict__ cnt,
                                                  float* __restrict__ out) {
    // Per-wave private staging: [wave][o:3584 | g:3584]. 28,672 B -> 5 blocks/CU.
    __shared__ __attribute__((aligned(16))) unsigned char ldsbuf[4 * kWaveTot];
    __shared__ float red[4];
    __shared__ unsigned int ticket;

    const int tid  = threadIdx.x;
    const int lane = tid & 63;
    const int wav  = tid >> 6;
    unsigned char* wBase = ldsbuf + wav * kWaveTot;

    float loss = 0.0f;

    // 3 contiguous chunks per block; each wave owns 64 contiguous cells per chunk.
    for (int j = 0; j < kChunksPerBlk; ++j) {
        const size_t chunk = (size_t)blockIdx.x * kChunksPerBlk + j;
        const size_t cell0 = chunk * kThreads + (size_t)wav * 64;
        const unsigned char* gO = reinterpret_cast<const unsigned char*>(outp) + cell0 * kCellB;
        const unsigned char* gG = reinterpret_cast<const unsigned char*>(gtp)  + cell0 * kCellB;

        if (j) {
            // Ensure prior chunk's ds_reads drained before overwriting LDS.
            asm volatile("s_waitcnt lgkmcnt(0)" ::: "memory");
            __builtin_amdgcn_sched_barrier(0);
        }

        // 7 x 1024 B transfers cover both tensors; transfer 3 splits lanes across o/g.
#pragma unroll
        for (int t = 0; t < 7; ++t) {
            const int p = t * 1024 + lane * 16;
            const unsigned char* src = (p < kWaveB) ? (gO + p) : (gG + (p - kWaveB));
            gl_lds16(src, wBase + t * 1024);
        }

        // Wave-private wait: only OUR loads; no block barrier.
        __builtin_amdgcn_wave_barrier();
        asm volatile("s_waitcnt vmcnt(0)" ::: "memory");
        __builtin_amdgcn_wave_barrier();

        // Cell base = 56*lane: 8-B aligned -> ds_read_b64 x7 per tensor.
        const float2* po = reinterpret_cast<const float2*>(wBase + lane * kCellB);
        const float2* pg = reinterpret_cast<const float2*>(wBase + kWaveB + lane * kCellB);

        float o[14], g[14];
#pragma unroll
        for (int k = 0; k < 7; ++k) {
            float2 a = po[k];
            float2 b = pg[k];
            o[2 * k] = a.x; o[2 * k + 1] = a.y;
            g[2 * k] = b.x; g[2 * k + 1] = b.y;
        }

        loss += cell_loss(o, g);
    }

    // wave64 tree reduce, then one cross-wave combine per block lifetime.
#pragma unroll
    for (int off = 32; off > 0; off >>= 1) loss += __shfl_down(loss, off, 64);
    if (lane == 0) red[wav] = loss;
    __syncthreads();
    if (tid == 0) {
        partial[blockIdx.x] = red[0] + red[1] + red[2] + red[3];
        // Release: partial store visible device-wide (across XCD L2s) before ticket.
        __threadfence();
        ticket = atomicAdd(cnt, 1u);   // device-scope by default
    }
    __syncthreads();

    if (ticket == kGrid - 1) {
        // Last block: all 2048 partials are globally visible. Reduce them here,
        // saving the second kernel launch + its tail latency.
        __shared__ double dred[4];
        double acc = 0.0;
        // 8 coalesced dword loads/thread, agent-scope (bypass possibly-stale L2).
#pragma unroll
        for (int k = 0; k < kGrid / kThreads; ++k) {
            float v = __hip_atomic_load(&partial[tid + k * kThreads],
                                        __ATOMIC_RELAXED, __HIP_MEMORY_SCOPE_AGENT);
            acc += (double)v;
        }
#pragma unroll
        for (int off = 32; off > 0; off >>= 1) acc += __shfl_down(acc, off, 64);
        if (lane == 0) dred[wav] = acc;
        __syncthreads();
        if (tid == 0)
            out[0] = (float)((dred[0] + dred[1] + dred[2] + dred[3]) * (1.0 / (double)kN));
    }
}

extern "C" void kernel_launch(void* const* d_in, const int* in_sizes, int n_in,
                              void* d_out, int out_size, void* d_ws, size_t ws_size,
                              hipStream_t stream) {
    const float* outp = (const float*)d_in[0];   // output: (N,H,W,C) fp32
    const float* gtp  = (const float*)d_in[1];   // ground_truth: (N,H,W,C) fp32
    float* partial    = (float*)d_ws;            // 2048 floats
    unsigned int* cnt = (unsigned int*)((char*)d_ws + kGrid * sizeof(float));
    float* out        = (float*)d_out;

    // Zero the ticket counter each iteration (graph-capturable async op).
    hipMemsetAsync(cnt, 0, sizeof(unsigned int), stream);
    yolo_fused<<<kGrid, kThreads, 0, stream>>>(outp, gtp, partial, cnt, out);
}

// Round 5
// 46.852 us; speedup vs baseline: 2.1019x; 2.1019x over previous
//
#include <hip/hip_runtime.h>

// Problem constants (from reference): N=32768, H=6, W=8, C=14
constexpr int kN        = 32768;
constexpr int kCells    = 32768 * 6 * 8;        // 1,572,864 cells
constexpr int kThreads  = 256;                  // 4 waves / block
constexpr int kGrid     = 2048;                 // blocks
constexpr int kChunksPerBlk = 3;                // 2048*256*3 = kCells (exact)
constexpr int kCellB    = 56;                   // 14 floats per cell
constexpr int kWaveB    = 64 * kCellB;          // 3584 B per tensor per wave
constexpr int kWaveTot  = 2 * kWaveB;           // 7168 B per wave (o + g)

constexpr float LAMBDA_COORD = 8.0f;
constexpr float LAMBDA_NOOBJ = 1.0f;
constexpr float LAMBDA_CLASS = 0.7f;
constexpr float EPS          = 1e-10f;

__device__ __forceinline__ float iou_box(float bx, float by, float bsw, float bsh,
                                         float gx, float gy, float gsw, float gsh) {
    float w1 = bsw * bsw, h1 = bsh * bsh;
    float w2 = gsw * gsw, h2 = gsh * gsh;
    float left  = fmaxf(bx - 0.5f * w1, gx - 0.5f * w2);
    float right = fminf(bx + 0.5f * w1, gx + 0.5f * w2);
    float top   = fmaxf(by - 0.5f * h1, gy - 0.5f * h2);
    float bot   = fminf(by + 0.5f * h1, gy + 0.5f * h2);
    float inter = fmaxf(right - left, 0.0f) * fmaxf(bot - top, 0.0f);
    float uni   = w1 * h1 + w2 * h2 - inter;
    return inter / (uni + EPS);
}

__device__ __forceinline__ float cell_loss(const float* o, const float* g) {
    float obj   = (g[4] > 0.0f) ? 1.0f : 0.0f;
    float noobj = 1.0f - obj;

    float iou0 = iou_box(o[0], o[1], o[2], o[3], g[0], g[1], g[2], g[3]);
    float iou1 = iou_box(o[5], o[6], o[7], o[8], g[0], g[1], g[2], g[3]);
    bool  s1   = iou1 > iou0;            // jnp.argmax picks first on ties -> idx=1 iff iou1>iou0
    float max_iou = fmaxf(iou0, iou1);

    float pr0 = s1 ? o[5] : o[0];
    float pr1 = s1 ? o[6] : o[1];
    float pr2 = s1 ? o[7] : o[2];
    float pr3 = s1 ? o[8] : o[3];
    float pr4 = s1 ? o[9] : o[4];
    float po4 = s1 ? o[4] : o[9];        // other pred conf

    float gr0 = s1 ? g[5] : g[0];
    float gr1 = s1 ? g[6] : g[1];
    float gr2 = s1 ? g[7] : g[2];
    float gr3 = s1 ? g[8] : g[3];
    float gn4 = s1 ? g[4] : g[9];        // other gt conf

    float d4 = o[4] - g[4], d9 = o[9] - g[9];
    float no_loss = noobj * (d4 * d4 + d9 * d9);

    float dcf  = pr4 - max_iou;
    float conf = dcf * dcf;

    float l0 = pr0 - gr0, l1 = pr1 - gr1, l2 = pr2 - gr2, l3 = pr3 - gr3;
    float loc = l0 * l0 + l1 * l1 + l2 * l2 + l3 * l3;

    float dnb = po4 - gn4;
    float nbc = dnb * dnb;

    float cls = 0.0f;
#pragma unroll
    for (int c = 10; c < 14; ++c) { float d = o[c] - g[c]; cls += d * d; }

    return LAMBDA_NOOBJ * no_loss +
           obj * (conf + LAMBDA_COORD * loc + LAMBDA_NOOBJ * nbc + LAMBDA_CLASS * cls);
}

// Async global->LDS, 16 B per lane. LDS dest = wave-uniform base + lane*16 (HW rule);
// GLOBAL source address is per-lane (may even point at different tensors per lane).
__device__ __forceinline__ void gl_lds16(const void* g, void* l) {
    __builtin_amdgcn_global_load_lds(
        (const __attribute__((address_space(1))) unsigned int*)g,
        (__attribute__((address_space(3))) unsigned int*)l,
        16 /*bytes, literal*/, 0 /*offset*/, 0 /*aux*/);
}

__global__ __launch_bounds__(256) void yolo_fused(const float* __restrict__ outp,
                                                  const float* __restrict__ gtp,
                                                  float* __restrict__ partial,
                                                  unsigned int* __restrict__ cnt,
                                                  float* __restrict__ out) {
    // Per-wave private staging: [wave][o:3584 | g:3584]. 28,672 B -> 5 blocks/CU.
    __shared__ __attribute__((aligned(16))) unsigned char ldsbuf[4 * kWaveTot];
    __shared__ float red[4];
    __shared__ unsigned int ticket;

    const int tid  = threadIdx.x;
    const int lane = tid & 63;
    const int wav  = tid >> 6;
    unsigned char* wBase = ldsbuf + wav * kWaveTot;

    float loss = 0.0f;

    // 3 contiguous chunks per block; each wave owns 64 contiguous cells per chunk.
    for (int j = 0; j < kChunksPerBlk; ++j) {
        const size_t chunk = (size_t)blockIdx.x * kChunksPerBlk + j;
        const size_t cell0 = chunk * kThreads + (size_t)wav * 64;
        const unsigned char* gO = reinterpret_cast<const unsigned char*>(outp) + cell0 * kCellB;
        const unsigned char* gG = reinterpret_cast<const unsigned char*>(gtp)  + cell0 * kCellB;

        if (j) {
            // Ensure prior chunk's ds_reads drained before overwriting LDS.
            asm volatile("s_waitcnt lgkmcnt(0)" ::: "memory");
            __builtin_amdgcn_sched_barrier(0);
        }

        // 7 x 1024 B transfers cover both tensors; transfer 3 splits lanes across o/g.
#pragma unroll
        for (int t = 0; t < 7; ++t) {
            const int p = t * 1024 + lane * 16;
            const unsigned char* src = (p < kWaveB) ? (gO + p) : (gG + (p - kWaveB));
            gl_lds16(src, wBase + t * 1024);
        }

        // Wave-private wait: only OUR loads; no block barrier.
        __builtin_amdgcn_wave_barrier();
        asm volatile("s_waitcnt vmcnt(0)" ::: "memory");
        __builtin_amdgcn_wave_barrier();

        // Cell base = 56*lane: 8-B aligned -> ds_read_b64 x7 per tensor.
        const float2* po = reinterpret_cast<const float2*>(wBase + lane * kCellB);
        const float2* pg = reinterpret_cast<const float2*>(wBase + kWaveB + lane * kCellB);

        float o[14], g[14];
#pragma unroll
        for (int k = 0; k < 7; ++k) {
            float2 a = po[k];
            float2 b = pg[k];
            o[2 * k] = a.x; o[2 * k + 1] = a.y;
            g[2 * k] = b.x; g[2 * k + 1] = b.y;
        }

        loss += cell_loss(o, g);
    }

    // wave64 tree reduce, then one cross-wave combine per block lifetime.
#pragma unroll
    for (int off = 32; off > 0; off >>= 1) loss += __shfl_down(loss, off, 64);
    if (lane == 0) red[wav] = loss;
    __syncthreads();
    if (tid == 0) {
        float p = red[0] + red[1] + red[2] + red[3];
        // Agent-scope relaxed atomic store: plain global_store with sc bits set ->
        // bypasses this XCD's (non-coherent) L2 straight to the coherent point.
        // NO buffer_wbl2 / buffer_inv (R4's 2.5x regression mechanism).
        __hip_atomic_store(&partial[blockIdx.x], p,
                           __ATOMIC_RELAXED, __HIP_MEMORY_SCOPE_AGENT);
        // Store ack'd at coherent point before the ticket RMW issues.
        asm volatile("s_waitcnt vmcnt(0)" ::: "memory");
        ticket = atomicAdd(cnt, 1u);   // device-scope RMW at coherent point
    }
    __syncthreads();

    if (ticket == kGrid - 1) {
        // Last block: all 2048 partials reached the coherent point (each block's
        // store completed before its ticket RMW). Agent-scope loads bypass our
        // possibly-stale L2. Saves the second kernel launch + tail.
        __shared__ double dred[4];
        double acc = 0.0;
#pragma unroll
        for (int k = 0; k < kGrid / kThreads; ++k) {
            float v = __hip_atomic_load(&partial[tid + k * kThreads],
                                        __ATOMIC_RELAXED, __HIP_MEMORY_SCOPE_AGENT);
            acc += (double)v;
        }
#pragma unroll
        for (int off = 32; off > 0; off >>= 1) acc += __shfl_down(acc, off, 64);
        if (lane == 0) dred[wav] = acc;
        __syncthreads();
        if (tid == 0)
            out[0] = (float)((dred[0] + dred[1] + dred[2] + dred[3]) * (1.0 / (double)kN));
    }
}

extern "C" void kernel_launch(void* const* d_in, const int* in_sizes, int n_in,
                              void* d_out, int out_size, void* d_ws, size_t ws_size,
                              hipStream_t stream) {
    const float* outp = (const float*)d_in[0];   // output: (N,H,W,C) fp32
    const float* gtp  = (const float*)d_in[1];   // ground_truth: (N,H,W,C) fp32
    float* partial    = (float*)d_ws;            // 2048 floats
    unsigned int* cnt = (unsigned int*)((char*)d_ws + kGrid * sizeof(float));
    float* out        = (float*)d_out;

    // Zero the ticket counter each iteration (graph-capturable async op).
    hipMemsetAsync(cnt, 0, sizeof(unsigned int), stream);
    yolo_fused<<<kGrid, kThreads, 0, stream>>>(outp, gtp, partial, cnt, out);
}

// Round 6
// 33.206 us; speedup vs baseline: 2.9656x; 1.4109x over previous
//
#include <hip/hip_runtime.h>

// Problem constants (from reference): N=32768, H=6, W=8, C=14
constexpr int kN        = 32768;
constexpr int kCells    = 32768 * 6 * 8;        // 1,572,864 cells
constexpr int kThreads  = 256;                  // 4 waves / block
constexpr int kGrid     = 2048;                 // blocks
constexpr int kChunksPerBlk = 3;                // 2048*256*3 = kCells (exact)
constexpr int kCellB    = 56;                   // 14 floats per cell
constexpr int kWaveB    = 64 * kCellB;          // 3584 B per tensor per wave
constexpr int kWaveTot  = 2 * kWaveB;           // 7168 B per wave (o + g)

constexpr float LAMBDA_COORD = 8.0f;
constexpr float LAMBDA_NOOBJ = 1.0f;
constexpr float LAMBDA_CLASS = 0.7f;
constexpr float EPS          = 1e-10f;

__device__ __forceinline__ float iou_box(float bx, float by, float bsw, float bsh,
                                         float gx, float gy, float gsw, float gsh) {
    float w1 = bsw * bsw, h1 = bsh * bsh;
    float w2 = gsw * gsw, h2 = gsh * gsh;
    float left  = fmaxf(bx - 0.5f * w1, gx - 0.5f * w2);
    float right = fminf(bx + 0.5f * w1, gx + 0.5f * w2);
    float top   = fmaxf(by - 0.5f * h1, gy - 0.5f * h2);
    float bot   = fminf(by + 0.5f * h1, gy + 0.5f * h2);
    float inter = fmaxf(right - left, 0.0f) * fmaxf(bot - top, 0.0f);
    float uni   = w1 * h1 + w2 * h2 - inter;
    return inter / (uni + EPS);
}

__device__ __forceinline__ float cell_loss(const float* o, const float* g) {
    float obj   = (g[4] > 0.0f) ? 1.0f : 0.0f;
    float noobj = 1.0f - obj;

    float iou0 = iou_box(o[0], o[1], o[2], o[3], g[0], g[1], g[2], g[3]);
    float iou1 = iou_box(o[5], o[6], o[7], o[8], g[0], g[1], g[2], g[3]);
    bool  s1   = iou1 > iou0;            // jnp.argmax picks first on ties -> idx=1 iff iou1>iou0
    float max_iou = fmaxf(iou0, iou1);

    float pr0 = s1 ? o[5] : o[0];
    float pr1 = s1 ? o[6] : o[1];
    float pr2 = s1 ? o[7] : o[2];
    float pr3 = s1 ? o[8] : o[3];
    float pr4 = s1 ? o[9] : o[4];
    float po4 = s1 ? o[4] : o[9];        // other pred conf

    float gr0 = s1 ? g[5] : g[0];
    float gr1 = s1 ? g[6] : g[1];
    float gr2 = s1 ? g[7] : g[2];
    float gr3 = s1 ? g[8] : g[3];
    float gn4 = s1 ? g[4] : g[9];        // other gt conf

    float d4 = o[4] - g[4], d9 = o[9] - g[9];
    float no_loss = noobj * (d4 * d4 + d9 * d9);

    float dcf  = pr4 - max_iou;
    float conf = dcf * dcf;

    float l0 = pr0 - gr0, l1 = pr1 - gr1, l2 = pr2 - gr2, l3 = pr3 - gr3;
    float loc = l0 * l0 + l1 * l1 + l2 * l2 + l3 * l3;

    float dnb = po4 - gn4;
    float nbc = dnb * dnb;

    float cls = 0.0f;
#pragma unroll
    for (int c = 10; c < 14; ++c) { float d = o[c] - g[c]; cls += d * d; }

    return LAMBDA_NOOBJ * no_loss +
           obj * (conf + LAMBDA_COORD * loc + LAMBDA_NOOBJ * nbc + LAMBDA_CLASS * cls);
}

// Async global->LDS, 16 B per lane. LDS dest = wave-uniform base + lane*16 (HW rule);
// GLOBAL source address is per-lane (may even point at different tensors per lane).
__device__ __forceinline__ void gl_lds16(const void* g, void* l) {
    __builtin_amdgcn_global_load_lds(
        (const __attribute__((address_space(1))) unsigned int*)g,
        (__attribute__((address_space(3))) unsigned int*)l,
        16 /*bytes, literal*/, 0 /*offset*/, 0 /*aux*/);
}

__global__ __launch_bounds__(256) void yolo_partial(const float* __restrict__ outp,
                                                    const float* __restrict__ gtp,
                                                    float* __restrict__ partial) {
    // Per-wave private staging: [wave][o:3584 | g:3584]. 28,672 B -> 5 blocks/CU.
    __shared__ __attribute__((aligned(16))) unsigned char lds[4 * kWaveTot];
    __shared__ float red[4];

    const int tid  = threadIdx.x;
    const int lane = tid & 63;
    const int wav  = tid >> 6;
    unsigned char* wBase = lds + wav * kWaveTot;

    float loss = 0.0f;

    // 3 contiguous chunks per block; each wave owns 64 contiguous cells per chunk.
    for (int j = 0; j < kChunksPerBlk; ++j) {
        const size_t chunk = (size_t)blockIdx.x * kChunksPerBlk + j;
        const size_t cell0 = chunk * kThreads + (size_t)wav * 64;
        const unsigned char* gO = reinterpret_cast<const unsigned char*>(outp) + cell0 * kCellB;
        const unsigned char* gG = reinterpret_cast<const unsigned char*>(gtp)  + cell0 * kCellB;

        if (j) {
            // Ensure prior chunk's ds_reads drained before overwriting LDS.
            asm volatile("s_waitcnt lgkmcnt(0)" ::: "memory");
            __builtin_amdgcn_sched_barrier(0);
        }

        // 7 x 1024 B transfers cover both tensors; transfer 3 splits lanes across o/g.
#pragma unroll
        for (int t = 0; t < 7; ++t) {
            const int p = t * 1024 + lane * 16;
            const unsigned char* src = (p < kWaveB) ? (gO + p) : (gG + (p - kWaveB));
            gl_lds16(src, wBase + t * 1024);
        }

        // Wave-private wait: only OUR loads; no block barrier.
        __builtin_amdgcn_wave_barrier();
        asm volatile("s_waitcnt vmcnt(0)" ::: "memory");
        __builtin_amdgcn_wave_barrier();

        // Cell base = 56*lane: 8-B aligned -> ds_read_b64 x7 per tensor.
        const float2* po = reinterpret_cast<const float2*>(wBase + lane * kCellB);
        const float2* pg = reinterpret_cast<const float2*>(wBase + kWaveB + lane * kCellB);

        float o[14], g[14];
#pragma unroll
        for (int k = 0; k < 7; ++k) {
            float2 a = po[k];
            float2 b = pg[k];
            o[2 * k] = a.x; o[2 * k + 1] = a.y;
            g[2 * k] = b.x; g[2 * k + 1] = b.y;
        }

        loss += cell_loss(o, g);
    }

    // wave64 tree reduce, then one cross-wave combine per block lifetime.
#pragma unroll
    for (int off = 32; off > 0; off >>= 1) loss += __shfl_down(loss, off, 64);
    if (lane == 0) red[wav] = loss;
    __syncthreads();
    if (tid == 0) partial[blockIdx.x] = red[0] + red[1] + red[2] + red[3];
}

// Single-wave finisher: 2048 floats = 512 float4; 8 independent float4 loads/lane,
// no LDS, no __syncthreads. Kernel-boundary coherence handles XCD visibility.
__global__ __launch_bounds__(64) void yolo_final(const float* __restrict__ partial,
                                                 float* __restrict__ out) {
    const float4* p4 = reinterpret_cast<const float4*>(partial);
    const int lane = threadIdx.x;
    double acc = 0.0;
#pragma unroll
    for (int k = 0; k < 8; ++k) {
        float4 v = p4[lane + k * 64];
        acc += (double)v.x + (double)v.y + (double)v.z + (double)v.w;
    }
#pragma unroll
    for (int off = 32; off > 0; off >>= 1) acc += __shfl_down(acc, off, 64);
    if (lane == 0) out[0] = (float)(acc * (1.0 / (double)kN));
}

extern "C" void kernel_launch(void* const* d_in, const int* in_sizes, int n_in,
                              void* d_out, int out_size, void* d_ws, size_t ws_size,
                              hipStream_t stream) {
    const float* outp = (const float*)d_in[0];   // output: (N,H,W,C) fp32
    const float* gtp  = (const float*)d_in[1];   // ground_truth: (N,H,W,C) fp32
    float* partial    = (float*)d_ws;            // 2048 floats = 8 KB scratch
    float* out        = (float*)d_out;

    yolo_partial<<<kGrid, kThreads, 0, stream>>>(outp, gtp, partial);
    yolo_final<<<1, 64, 0, stream>>>(partial, out);
}